// Round 2
// baseline (428.212 us; speedup 1.0000x reference)
//
#include <hip/hip_runtime.h>

#define BATCH   256
#define DIMS    64
#define LEVELS  100
#define HVD     10000
#define WH      64        // h-tile columns per block
#define NHT     157       // ceil(HVD/WH)
#define DSPLIT  8         // d-splits (blocks along y)
#define DPER    8         // dims per split
#define LSTRIDE 68        // padded floats per level row in LDS (breaks bank aliasing)

// ---------------------------------------------------------------------------
// Encode: block = (h-tile of 64 cols, d-split of 8 dims), ALL 256 batches.
// Each base element is fetched from HBM exactly once, coalesced, by exactly
// one block (no cross-block sharing -> cache-independent traffic = 256 MB).
// Thread t: batch-group g = t>>4 (16 batches g*16..g*16+15), cols ci=(t&15)*4.
// Accumulators: 16 x float4 in registers.
// ---------------------------------------------------------------------------
__global__ __launch_bounds__(256) void encode_kernel(
    const float* __restrict__ x,
    const float* __restrict__ base,
    float* __restrict__ partial)          // [DSPLIT][BATCH][HVD]
{
    __shared__ float s_chunk[LEVELS * LSTRIDE];   // 27.2 KB, one d at a time
    __shared__ int   s_lohi[DPER][BATCH];         // lo*LSTRIDE | (hi*LSTRIDE)<<16
    __shared__ float s_a[DPER][BATCH];            // alpha

    const int tid   = threadIdx.x;
    const int htile = blockIdx.x;
    const int split = blockIdx.y;
    const int h0    = htile * WH;
    const int d0    = split * DPER;

    // Interpolation params for this block's 8 dims x 256 batches (8/thread).
    for (int k = 0; k < DPER; ++k) {
        const int dl = k;
        const int b  = tid;
        float xv = x[b * DIMS + d0 + dl];
        float xn = fminf(fmaxf(xv * (float)(LEVELS - 1), 0.0f), (float)(LEVELS - 1));
        float fl = floorf(xn);
        int   lo = (int)fl;
        int   hi = lo < LEVELS - 1 ? lo + 1 : LEVELS - 1;
        s_lohi[dl][b] = (lo * LSTRIDE) | ((hi * LSTRIDE) << 16);
        s_a[dl][b]    = xn - fl;
    }

    const int g  = tid >> 4;           // 0..15 batch group
    const int ci = (tid & 15) * 4;     // col offset within tile (float4)
    const int wvalid = (HVD - h0) < WH ? (HVD - h0) : WH;   // 64, or 16 on tail

    float4 acc[16];
    #pragma unroll
    for (int j = 0; j < 16; ++j) acc[j] = make_float4(0.f, 0.f, 0.f, 0.f);

    for (int dc = 0; dc < DPER; ++dc) {
        __syncthreads();   // previous chunk consumed (covers params on iter 0)

        // Stage base[d0+dc, 0:100, h0:h0+wvalid] -> LDS, fully coalesced.
        const float* src = base + ((size_t)(d0 + dc) * LEVELS) * (size_t)HVD + h0;
        for (int i = tid; i < LEVELS * (WH / 4); i += 256) {
            const int l  = i >> 4;           // level
            const int cc = (i & 15) * 4;     // col
            if (cc < wvalid) {
                float4 v = *(const float4*)(src + (size_t)l * HVD + cc);
                *(float4*)(&s_chunk[l * LSTRIDE + cc]) = v;
            }
        }
        __syncthreads();

        #pragma unroll
        for (int j = 0; j < 16; ++j) {
            const int   b    = g * 16 + j;
            const int   lohi = s_lohi[dc][b];     // wave: 4 broadcast addrs
            const float a    = s_a[dc][b];
            const int   olo  = lohi & 0xffff;
            const int   ohi  = lohi >> 16;
            const float wl   = 1.0f - a;
            float4 vlo = *(const float4*)(&s_chunk[olo + ci]);
            float4 vhi = *(const float4*)(&s_chunk[ohi + ci]);
            acc[j].x += wl * vlo.x + a * vhi.x;
            acc[j].y += wl * vlo.y + a * vhi.y;
            acc[j].z += wl * vlo.z + a * vhi.z;
            acc[j].w += wl * vlo.w + a * vhi.w;
        }
    }

    // Write partial sums (coalesced 256 B per 16-lane group).
    if (ci < wvalid) {
        float* dst = partial + ((size_t)split * BATCH) * (size_t)HVD + h0 + ci;
        #pragma unroll
        for (int j = 0; j < 16; ++j) {
            const int b = g * 16 + j;
            *(float4*)(dst + (size_t)b * HVD) = acc[j];
        }
    }
}

// ---------------------------------------------------------------------------
// Finish: per batch row, sum the 8 partials, L2-normalize, write d_out.
// ---------------------------------------------------------------------------
__global__ __launch_bounds__(256) void finish_kernel(
    const float* __restrict__ partial,    // [DSPLIT][BATCH][HVD]
    float* __restrict__ out)              // [BATCH][HVD]
{
    const int b   = blockIdx.x;
    const int tid = threadIdx.x;

    float ss = 0.f;
    for (int i = tid; i < HVD / 4; i += 256) {
        float4 s = make_float4(0.f, 0.f, 0.f, 0.f);
        #pragma unroll
        for (int sp = 0; sp < DSPLIT; ++sp) {
            const float4 v = *(const float4*)(partial +
                ((size_t)sp * BATCH + b) * (size_t)HVD + i * 4);
            s.x += v.x; s.y += v.y; s.z += v.z; s.w += v.w;
        }
        *(float4*)(out + (size_t)b * HVD + i * 4) = s;
        ss += s.x * s.x + s.y * s.y + s.z * s.z + s.w * s.w;
    }

    __shared__ float red[256];
    red[tid] = ss;
    __syncthreads();
    #pragma unroll
    for (int s = 128; s > 0; s >>= 1) {
        if (tid < s) red[tid] += red[tid + s];
        __syncthreads();
    }
    const float inv = rsqrtf(red[0]);

    // Each thread rescales exactly the positions it wrote (no cross-thread
    // hazard; the reduction barrier above ordered pass 1 vs pass 2).
    for (int i = tid; i < HVD / 4; i += 256) {
        float4 v = *(float4*)(out + (size_t)b * HVD + i * 4);
        v.x *= inv; v.y *= inv; v.z *= inv; v.w *= inv;
        *(float4*)(out + (size_t)b * HVD + i * 4) = v;
    }
}

extern "C" void kernel_launch(void* const* d_in, const int* in_sizes, int n_in,
                              void* d_out, int out_size, void* d_ws, size_t ws_size,
                              hipStream_t stream)
{
    const float* x    = (const float*)d_in[0];   // (256, 64)
    const float* base = (const float*)d_in[1];   // (64, 100, 10000)
    float*       out  = (float*)d_out;           // (256, 10000)
    float*       part = (float*)d_ws;            // DSPLIT*BATCH*HVD floats = 82 MB

    dim3 grid(NHT, DSPLIT);
    encode_kernel<<<grid, 256, 0, stream>>>(x, base, part);
    finish_kernel<<<BATCH, 256, 0, stream>>>(part, out);
}

// Round 3
// 393.130 us; speedup vs baseline: 1.0892x; 1.0892x over previous
//
#include <hip/hip_runtime.h>
#include <hip/hip_fp16.h>

#define BATCH   256
#define DIMS    64
#define LEVELS  100
#define HVD     10000
#define WH      128       // h-tile columns (floats) per block
#define NHT     79        // ceil(HVD/WH): 78*128=9984, tail tile has 16 cols
#define DSPLIT  8         // d-splits
#define DPER    8         // dims per split
#define TPB     512       // 8 waves

// ---------------------------------------------------------------------------
// Encode: block = (h-tile 128 cols, d-split of 8 dims) x ALL 256 batches.
// Wave w owns batches w*32..w*32+31; lane L covers cols {2L, 2L+1}.
// All LDS value reads are wave-uniform-row + contiguous 512 B -> conflict-free.
// Staging: HBM -> LDS via global_load_lds width=16 (no VGPR round-trip);
// chunk layout is exact row-major stride 128 floats (lane x 16 B contiguous).
// Each base byte is fetched exactly once, by exactly one block, coalesced.
// ---------------------------------------------------------------------------
__global__ __launch_bounds__(TPB, 4) void encode_kernel(
    const float* __restrict__ x,
    const float* __restrict__ base,
    float* __restrict__ partial)          // [DSPLIT][BATCH][HVD]
{
    __shared__ float    s_chunk[LEVELS * WH];     // 51.2 KB, row r at r*WH
    __shared__ unsigned s_prm[DPER][BATCH];       // fp16(alpha) | lo<<16 | hi<<24 (8 KB)

    const int tid   = threadIdx.x;
    const int w     = tid >> 6;               // wave 0..7
    const int lane  = tid & 63;
    const int htile = blockIdx.x;
    const int split = blockIdx.y;
    const int h0    = htile * WH;
    const int d0    = split * DPER;
    const int wvalid = (HVD - h0) < WH ? (HVD - h0) : WH;

    // Interpolation params: 8 dims x 256 batches, packed to 4 B each.
    for (int i = tid; i < DPER * BATCH; i += TPB) {
        const int dl = i >> 8;
        const int b  = i & 255;
        float xv = x[b * DIMS + d0 + dl];
        float xn = fminf(fmaxf(xv * (float)(LEVELS - 1), 0.0f), (float)(LEVELS - 1));
        float fl = floorf(xn);
        int   lo = (int)fl;
        int   hi = lo < LEVELS - 1 ? lo + 1 : LEVELS - 1;
        unsigned abits = (unsigned)__half_as_ushort(__float2half(xn - fl));
        s_prm[dl][b] = abits | ((unsigned)lo << 16) | ((unsigned)hi << 24);
    }

    const int cix   = lane * 2;               // col pair for value reads
    const int bbase = w * 32;
    const int srow  = lane >> 5;              // staging: row within pair
    const int scol  = (lane & 31) * 4;        // staging: float col

    float2 acc[32];
    #pragma unroll
    for (int j = 0; j < 32; ++j) acc[j] = make_float2(0.f, 0.f);

    #pragma unroll 1
    for (int dc = 0; dc < DPER; ++dc) {
        __syncthreads();   // prev chunk consumed (covers params on dc=0)

        // Stage base[d0+dc, 0:100, h0:h0+wvalid]: 50 row-pairs, 1 KB per instr.
        const float* src = base + ((size_t)(d0 + dc) * LEVELS) * (size_t)HVD + h0;
        for (int p = w; p < LEVELS / 2; p += 8) {
            const float* g = src + (size_t)(2 * p + srow) * HVD + scol;
            if (scol < wvalid) {
                __builtin_amdgcn_global_load_lds(
                    (const __attribute__((address_space(1))) unsigned*)g,
                    (__attribute__((address_space(3))) unsigned*)&s_chunk[p * 2 * WH],
                    16, 0, 0);
            }
        }
        __syncthreads();   // drains vmcnt -> chunk visible

        #pragma unroll
        for (int jj = 0; jj < 16; ++jj) {
            // two batches per iteration; param read is a uniform b64 broadcast
            uint2 pr = *(const uint2*)&s_prm[dc][bbase + 2 * jj];
            {
                const unsigned pk = pr.x;
                const float a  = __half2float(__ushort_as_half((unsigned short)(pk & 0xffffu)));
                const int olo  = (int)((pk >> 16) & 0xffu) * WH;
                const int ohi  = (int)(pk >> 24) * WH;
                float2 vlo = *(const float2*)&s_chunk[olo + cix];
                float2 vhi = *(const float2*)&s_chunk[ohi + cix];
                const float wl = 1.0f - a;
                acc[2 * jj].x += wl * vlo.x + a * vhi.x;
                acc[2 * jj].y += wl * vlo.y + a * vhi.y;
            }
            {
                const unsigned pk = pr.y;
                const float a  = __half2float(__ushort_as_half((unsigned short)(pk & 0xffffu)));
                const int olo  = (int)((pk >> 16) & 0xffu) * WH;
                const int ohi  = (int)(pk >> 24) * WH;
                float2 vlo = *(const float2*)&s_chunk[olo + cix];
                float2 vhi = *(const float2*)&s_chunk[ohi + cix];
                const float wl = 1.0f - a;
                acc[2 * jj + 1].x += wl * vlo.x + a * vhi.x;
                acc[2 * jj + 1].y += wl * vlo.y + a * vhi.y;
            }
        }
    }

    // Partial write: per instr, 64 lanes x 8 B = 512 B contiguous.
    if (cix < wvalid) {
        float* dst = partial + ((size_t)split * BATCH) * (size_t)HVD + h0 + cix;
        #pragma unroll
        for (int j = 0; j < 32; ++j)
            *(float2*)(dst + (size_t)(bbase + j) * HVD) = acc[j];
    }
}

// ---------------------------------------------------------------------------
// Finish: per batch row, sum the 8 partials, L2-normalize, write d_out.
// ---------------------------------------------------------------------------
__global__ __launch_bounds__(256) void finish_kernel(
    const float* __restrict__ partial,    // [DSPLIT][BATCH][HVD]
    float* __restrict__ out)              // [BATCH][HVD]
{
    const int b   = blockIdx.x;
    const int tid = threadIdx.x;

    float ss = 0.f;
    for (int i = tid; i < HVD / 4; i += 256) {
        float4 s = make_float4(0.f, 0.f, 0.f, 0.f);
        #pragma unroll
        for (int sp = 0; sp < DSPLIT; ++sp) {
            const float4 v = *(const float4*)(partial +
                ((size_t)sp * BATCH + b) * (size_t)HVD + i * 4);
            s.x += v.x; s.y += v.y; s.z += v.z; s.w += v.w;
        }
        *(float4*)(out + (size_t)b * HVD + i * 4) = s;
        ss += s.x * s.x + s.y * s.y + s.z * s.z + s.w * s.w;
    }

    __shared__ float red[256];
    red[tid] = ss;
    __syncthreads();
    #pragma unroll
    for (int s = 128; s > 0; s >>= 1) {
        if (tid < s) red[tid] += red[tid + s];
        __syncthreads();
    }
    const float inv = rsqrtf(red[0]);

    for (int i = tid; i < HVD / 4; i += 256) {
        float4 v = *(float4*)(out + (size_t)b * HVD + i * 4);
        v.x *= inv; v.y *= inv; v.z *= inv; v.w *= inv;
        *(float4*)(out + (size_t)b * HVD + i * 4) = v;
    }
}

extern "C" void kernel_launch(void* const* d_in, const int* in_sizes, int n_in,
                              void* d_out, int out_size, void* d_ws, size_t ws_size,
                              hipStream_t stream)
{
    const float* x    = (const float*)d_in[0];   // (256, 64)
    const float* base = (const float*)d_in[1];   // (64, 100, 10000)
    float*       out  = (float*)d_out;           // (256, 10000)
    float*       part = (float*)d_ws;            // 8*256*10000 floats = 82 MB

    dim3 grid(NHT, DSPLIT);
    encode_kernel<<<grid, TPB, 0, stream>>>(x, base, part);
    finish_kernel<<<BATCH, 256, 0, stream>>>(part, out);
}

// Round 4
// 383.359 us; speedup vs baseline: 1.1170x; 1.0255x over previous
//
#include <hip/hip_runtime.h>
#include <hip/hip_bf16.h>

#define BATCH   256
#define DIMS    64
#define LEVELS  100
#define HVD     10000
#define WH      128       // h-tile columns (floats) per block
#define NHT     79        // ceil(HVD/WH): 78 full tiles + 16-col tail
#define DSPLIT  8
#define DPER    8
#define TPB     512       // 8 waves

typedef unsigned int  uint;
typedef unsigned short ushort;

// d_ws layout: [0, 40.96 MB) bf16 partial [DSPLIT][BATCH][HVD]
//              [40.96 MB, +128 KB) uint2 params [DIMS][BATCH]
#define PRM_OFF_BYTES (DSPLIT * BATCH * HVD * 2)

static __device__ __forceinline__ ushort f2bf(float f) {
    __hip_bfloat16 h = __float2bfloat16(f);   // RNE
    return *reinterpret_cast<ushort*>(&h);
}

// ---------------------------------------------------------------------------
// Setup: pack per-(d,b) interpolation params. olo/ohi pre-scaled to LDS byte
// offsets (lo*WH*4 <= 50688, fits 16 bits). alpha kept full fp32.
// ---------------------------------------------------------------------------
__global__ __launch_bounds__(256) void setup_kernel(
    const float* __restrict__ x, uint2* __restrict__ prm)
{
    const int i = blockIdx.x * 256 + threadIdx.x;   // i = d*256 + b
    if (i >= DIMS * BATCH) return;
    const int d = i >> 8;
    const int b = i & 255;
    float xv = x[b * DIMS + d];
    float xn = fminf(fmaxf(xv * (float)(LEVELS - 1), 0.0f), (float)(LEVELS - 1));
    float fl = floorf(xn);
    int   lo = (int)fl;
    int   hi = lo < LEVELS - 1 ? lo + 1 : LEVELS - 1;
    prm[i] = make_uint2((uint)(lo * WH * 4) | ((uint)(hi * WH * 4) << 16),
                        __float_as_uint(xn - fl));
}

// ---------------------------------------------------------------------------
// Encode: block = (h-tile 128 cols, d-split of 8 dims) x ALL 256 batches.
// Wave w owns batches w*32..w*32+31. Lane = (sub s = lane>>5) x (col-quad
// c = lane&31): value reads are ds_read_b128, 2 rows/instr (free 2-way).
// Params arrive via wave-uniform s_load (SGPRs) -> no LDS latency chain.
// Staging: HBM -> LDS global_load_lds width=16, exact row-major layout.
// Each base byte fetched exactly once, by exactly one block, coalesced.
// ---------------------------------------------------------------------------
__global__ __launch_bounds__(TPB, 4) void encode_kernel(
    const float* __restrict__ base,
    const uint2* __restrict__ prm,
    ushort*      __restrict__ partial)     // bf16 [DSPLIT][BATCH][HVD]
{
    __shared__ float s_chunk[LEVELS * WH];        // 51.2 KB, row r at r*WH

    const int tid   = threadIdx.x;
    const int w     = tid >> 6;
    const int lane  = tid & 63;
    const int htile = blockIdx.x;
    const int split = blockIdx.y;
    const int h0    = htile * WH;
    const int d0    = split * DPER;
    const int wvalid = (HVD - h0) < WH ? (HVD - h0) : WH;

    const int wu    = __builtin_amdgcn_readfirstlane(w);  // provably uniform
    const int bbase = wu * 32;

    const int s   = lane >> 5;            // batch sub 0/1
    const int c   = lane & 31;            // col quad
    const int cb  = c * 16;               // byte offset of the quad
    const int c4  = c * 4;                // float col
    const int srow = lane >> 5;           // staging row-in-pair
    const int scol = (lane & 31) * 4;     // staging float col

    float4 acc[16];
    #pragma unroll
    for (int j = 0; j < 16; ++j) acc[j] = make_float4(0.f, 0.f, 0.f, 0.f);

    #pragma unroll 1
    for (int dc = 0; dc < DPER; ++dc) {
        __syncthreads();   // previous chunk fully consumed

        // Stage base[d0+dc, 0:100, h0:h0+wvalid]: 50 row-pairs, 1 KB/instr.
        const float* src = base + ((size_t)(d0 + dc) * LEVELS) * (size_t)HVD + h0;
        for (int p = w; p < LEVELS / 2; p += 8) {
            const float* g = src + (size_t)(2 * p + srow) * HVD + scol;
            if (scol < wvalid) {
                __builtin_amdgcn_global_load_lds(
                    (const __attribute__((address_space(1))) uint*)g,
                    (__attribute__((address_space(3))) uint*)&s_chunk[p * 2 * WH],
                    16, 0, 0);
            }
        }
        __syncthreads();   // drains vmcnt -> chunk visible

        const uint2* pr = prm + (size_t)(d0 + dc) * BATCH + bbase;  // uniform

        #pragma unroll
        for (int jj = 0; jj < 16; ++jj) {
            // batches bbase+2jj (sub 0) and bbase+2jj+1 (sub 1): one s_load_x4
            const uint4 pq = *(const uint4*)(pr + 2 * jj);
            const uint  lohi = s ? pq.z : pq.x;
            const float a    = __uint_as_float(s ? pq.w : pq.y);
            const int   olo  = (int)(lohi & 0xffffu);
            const int   ohi  = (int)(lohi >> 16);
            const float4 vlo = *(const float4*)((const char*)s_chunk + olo + cb);
            const float4 vhi = *(const float4*)((const char*)s_chunk + ohi + cb);
            const float wl = 1.0f - a;
            acc[jj].x += wl * vlo.x + a * vhi.x;
            acc[jj].y += wl * vlo.y + a * vhi.y;
            acc[jj].z += wl * vlo.z + a * vhi.z;
            acc[jj].w += wl * vlo.w + a * vhi.w;
        }
    }

    // Write bf16 partials: per instr, 2 batch-rows x 256 B contiguous.
    if (c4 < wvalid) {
        #pragma unroll
        for (int jj = 0; jj < 16; ++jj) {
            const int b = bbase + 2 * jj + s;
            uint2 pk;
            pk.x = (uint)f2bf(acc[jj].x) | ((uint)f2bf(acc[jj].y) << 16);
            pk.y = (uint)f2bf(acc[jj].z) | ((uint)f2bf(acc[jj].w) << 16);
            *(uint2*)(partial + ((size_t)split * BATCH + b) * (size_t)HVD + h0 + c4) = pk;
        }
    }
}

// ---------------------------------------------------------------------------
// Finish: per batch row, sum the 8 bf16 partials, L2-normalize, write out.
// ---------------------------------------------------------------------------
__global__ __launch_bounds__(256) void finish_kernel(
    const ushort* __restrict__ partial,    // bf16 [DSPLIT][BATCH][HVD]
    float* __restrict__ out)               // fp32 [BATCH][HVD]
{
    const int b   = blockIdx.x;
    const int tid = threadIdx.x;

    float ss = 0.f;
    for (int i = tid; i < HVD / 4; i += 256) {
        float4 sum = make_float4(0.f, 0.f, 0.f, 0.f);
        #pragma unroll
        for (int sp = 0; sp < DSPLIT; ++sp) {
            const uint2 u = *(const uint2*)(partial +
                ((size_t)sp * BATCH + b) * (size_t)HVD + i * 4);
            sum.x += __uint_as_float(u.x << 16);
            sum.y += __uint_as_float(u.x & 0xffff0000u);
            sum.z += __uint_as_float(u.y << 16);
            sum.w += __uint_as_float(u.y & 0xffff0000u);
        }
        *(float4*)(out + (size_t)b * HVD + i * 4) = sum;
        ss += sum.x * sum.x + sum.y * sum.y + sum.z * sum.z + sum.w * sum.w;
    }

    __shared__ float red[256];
    red[tid] = ss;
    __syncthreads();
    #pragma unroll
    for (int sh = 128; sh > 0; sh >>= 1) {
        if (tid < sh) red[tid] += red[tid + sh];
        __syncthreads();
    }
    const float inv = rsqrtf(red[0]);

    for (int i = tid; i < HVD / 4; i += 256) {
        float4 v = *(float4*)(out + (size_t)b * HVD + i * 4);
        v.x *= inv; v.y *= inv; v.z *= inv; v.w *= inv;
        *(float4*)(out + (size_t)b * HVD + i * 4) = v;
    }
}

extern "C" void kernel_launch(void* const* d_in, const int* in_sizes, int n_in,
                              void* d_out, int out_size, void* d_ws, size_t ws_size,
                              hipStream_t stream)
{
    const float* x    = (const float*)d_in[0];   // (256, 64)
    const float* base = (const float*)d_in[1];   // (64, 100, 10000)
    float*       out  = (float*)d_out;           // (256, 10000)
    ushort*      part = (ushort*)d_ws;                            // bf16 partials
    uint2*       prm  = (uint2*)((char*)d_ws + PRM_OFF_BYTES);    // packed params

    setup_kernel<<<DIMS, 256, 0, stream>>>(x, prm);
    dim3 grid(NHT, DSPLIT);
    encode_kernel<<<grid, TPB, 0, stream>>>(base, prm, part);
    finish_kernel<<<BATCH, 256, 0, stream>>>(part, out);
}

// Round 5
// 381.408 us; speedup vs baseline: 1.1227x; 1.0051x over previous
//
#include <hip/hip_runtime.h>
#include <hip/hip_fp16.h>
#include <hip/hip_bf16.h>

#define BATCH   256
#define DIMS    64
#define LEVELS  100
#define HVD     10000
#define WH      64        // h-tile columns per block
#define NHT     157       // ceil(HVD/WH); tile 156 has 16 valid cols
#define DSPLIT  8
#define DPER    8
#define TPB     256       // 4 waves
#define CHUNK_FLOATS (LEVELS * WH)            // 6400 floats = 25.6 KB
#define NSTG    25        // staging instrs per chunk (100 rows / 4 rows per instr)

typedef unsigned int   uint;
typedef unsigned short ushort;

// d_ws layout: [0, 40.96 MB) bf16 partial [DSPLIT][BATCH][HVD]
//              [40.96 MB, +64 KB) uint params [DIMS][BATCH]
#define PRM_OFF_BYTES (DSPLIT * BATCH * HVD * 2)

static __device__ __forceinline__ ushort f2bf(float f) {
    __hip_bfloat16 h = __float2bfloat16(f);   // RNE
    return *reinterpret_cast<ushort*>(&h);
}

// ---------------------------------------------------------------------------
// Setup: per-(d,b) params packed to 4 B: fp16(alpha) | lo<<16 | hi<<24.
// ---------------------------------------------------------------------------
__global__ __launch_bounds__(256) void setup_kernel(
    const float* __restrict__ x, uint* __restrict__ prm)
{
    const int i = blockIdx.x * 256 + threadIdx.x;   // i = d*256 + b
    if (i >= DIMS * BATCH) return;
    const int d = i >> 8;
    const int b = i & 255;
    float xv = x[b * DIMS + d];
    float xn = fminf(fmaxf(xv * (float)(LEVELS - 1), 0.0f), (float)(LEVELS - 1));
    float fl = floorf(xn);
    int   lo = (int)fl;
    int   hi = lo < LEVELS - 1 ? lo + 1 : LEVELS - 1;
    uint abits = (uint)__half_as_ushort(__float2half(xn - fl));
    prm[i] = abits | ((uint)lo << 16) | ((uint)hi << 24);
}

// ---------------------------------------------------------------------------
// Encode: block = (h-tile 64 cols, d-split of 8 dims) x ALL 256 batches.
// NEVER-DRAIN K-loop: double-buffered LDS chunks staged via global_load_lds,
// raw s_barrier + manual s_waitcnt vmcnt(N) so the next chunk's loads stay
// in flight through every compute phase (HBM duty cycle ~100%).
// Per wave, loads/chunk = 7 (wave 0) or 6 (waves 1-3); waiting vmcnt(6)
// completes the current chunk for all waves (wave 0 over-waits by 1 load).
// The K-loop issues NO other vmcnt ops (params pre-staged in LDS), so the
// manual counts are exact. Each base byte fetched once, coalesced.
// ---------------------------------------------------------------------------
__global__ __launch_bounds__(TPB, 2) void encode_kernel(
    const float* __restrict__ base,
    const uint* __restrict__ prm,
    ushort*     __restrict__ partial)      // bf16 [DSPLIT][BATCH][HVD]
{
    __shared__ float s_buf[2][CHUNK_FLOATS];   // 51.2 KB
    __shared__ uint  s_prm[DPER][BATCH];       // 8 KB

    const int tid   = threadIdx.x;
    const int w     = tid >> 6;            // wave 0..3
    const int lane  = tid & 63;
    const int htile = blockIdx.x;
    const int split = blockIdx.y;
    const int h0    = htile * WH;
    const int d0    = split * DPER;
    const int wvalid = (HVD - h0) < WH ? (HVD - h0) : WH;

    // Params -> LDS (vector loads; fully drained by the __syncthreads below,
    // so they never pollute the K-loop's vmcnt bookkeeping).
    {
        const uint4* pg = (const uint4*)(prm + d0 * BATCH);
        uint4* pl = (uint4*)&s_prm[0][0];
        for (int i = tid; i < DPER * BATCH / 4; i += TPB) pl[i] = pg[i];
    }
    __syncthreads();   // params visible; all counters drained

    const int srow = lane >> 4;            // staging: row within 4-row group
    const int scol = (lane & 15) * 4;      // staging: float col
    const float* srcdim = base + (size_t)d0 * LEVELS * HVD + h0;

    auto issue_chunk = [&](int dc, int bufidx) {
        const float* src = srcdim + (size_t)dc * LEVELS * HVD;
        float* dst = &s_buf[bufidx][0];
        for (int p = w; p < NSTG; p += 4) {          // wave0:7, waves1-3:6
            const float* g = src + (size_t)(4 * p + srow) * HVD + scol;
            if (scol < wvalid) {                      // lane mask; instr still issues
                __builtin_amdgcn_global_load_lds(
                    (const __attribute__((address_space(1))) uint*)g,
                    (__attribute__((address_space(3))) uint*)(dst + p * 4 * WH),
                    16, 0, 0);
            }
        }
    };

    issue_chunk(0, 0);
    issue_chunk(1, 1);

    const int sub   = lane >> 5;           // batch sub 0/1
    const int p2    = lane & 31;           // col pair (2 floats)
    const int pb    = p2 * 8;              // byte offset within a 256 B row
    const int bbase = w * 64;              // this wave's 64 batches

    float2 acc[32];
    #pragma unroll
    for (int j = 0; j < 32; ++j) acc[j] = make_float2(0.f, 0.f);

    #pragma unroll 1
    for (int dc = 0; dc < DPER; ++dc) {
        // Wait for chunk dc only; chunk dc+1's loads remain in flight.
        if (dc < DPER - 1) asm volatile("s_waitcnt vmcnt(6)" ::: "memory");
        else               asm volatile("s_waitcnt vmcnt(0)" ::: "memory");
        __builtin_amdgcn_s_barrier();      // all waves' chunk-dc portions landed

        const char* buf = (const char*)&s_buf[dc & 1][0];
        #pragma unroll
        for (int j = 0; j < 32; ++j) {
            uint2 pp = *(const uint2*)&s_prm[dc][bbase + 2 * j];  // b64 broadcast
            const uint pk = sub ? pp.y : pp.x;
            const float a = __half2float(__ushort_as_half((ushort)(pk & 0xffffu)));
            const int olo = (int)((pk >> 16) & 0xffu) << 8;   // lo * 256 B
            const int ohi = (int)(pk >> 24) << 8;             // hi * 256 B
            const float2 vlo = *(const float2*)(buf + olo + pb);
            const float2 vhi = *(const float2*)(buf + ohi + pb);
            const float wl = 1.0f - a;
            acc[j].x += wl * vlo.x + a * vhi.x;
            acc[j].y += wl * vlo.y + a * vhi.y;
        }
        asm volatile("" ::: "memory");     // pin reads before the reuse barrier
        __builtin_amdgcn_s_barrier();      // all waves done reading buf[dc&1]
        if (dc < DPER - 2) issue_chunk(dc + 2, dc & 1);   // overwrite freed buffer
    }

    // bf16 partial store: per instr, 2 batch-rows x 128 B contiguous.
    if (p2 * 2 < wvalid) {
        #pragma unroll
        for (int j = 0; j < 32; ++j) {
            const int b = bbase + 2 * j + sub;
            const uint pk = (uint)f2bf(acc[j].x) | ((uint)f2bf(acc[j].y) << 16);
            *(uint*)(partial + ((size_t)split * BATCH + b) * (size_t)HVD + h0 + p2 * 2) = pk;
        }
    }
}

// ---------------------------------------------------------------------------
// Finish: per batch row, sum the 8 bf16 partials, L2-normalize, write out.
// ---------------------------------------------------------------------------
__global__ __launch_bounds__(256) void finish_kernel(
    const ushort* __restrict__ partial,    // bf16 [DSPLIT][BATCH][HVD]
    float* __restrict__ out)               // fp32 [BATCH][HVD]
{
    const int b   = blockIdx.x;
    const int tid = threadIdx.x;

    float ss = 0.f;
    for (int i = tid; i < HVD / 4; i += 256) {
        float4 sum = make_float4(0.f, 0.f, 0.f, 0.f);
        #pragma unroll
        for (int sp = 0; sp < DSPLIT; ++sp) {
            const uint2 u = *(const uint2*)(partial +
                ((size_t)sp * BATCH + b) * (size_t)HVD + i * 4);
            sum.x += __uint_as_float(u.x << 16);
            sum.y += __uint_as_float(u.x & 0xffff0000u);
            sum.z += __uint_as_float(u.y << 16);
            sum.w += __uint_as_float(u.y & 0xffff0000u);
        }
        *(float4*)(out + (size_t)b * HVD + i * 4) = sum;
        ss += sum.x * sum.x + sum.y * sum.y + sum.z * sum.z + sum.w * sum.w;
    }

    __shared__ float red[256];
    red[tid] = ss;
    __syncthreads();
    #pragma unroll
    for (int sh = 128; sh > 0; sh >>= 1) {
        if (tid < sh) red[tid] += red[tid + sh];
        __syncthreads();
    }
    const float inv = rsqrtf(red[0]);

    for (int i = tid; i < HVD / 4; i += 256) {
        float4 v = *(float4*)(out + (size_t)b * HVD + i * 4);
        v.x *= inv; v.y *= inv; v.z *= inv; v.w *= inv;
        *(float4*)(out + (size_t)b * HVD + i * 4) = v;
    }
}

extern "C" void kernel_launch(void* const* d_in, const int* in_sizes, int n_in,
                              void* d_out, int out_size, void* d_ws, size_t ws_size,
                              hipStream_t stream)
{
    const float* x    = (const float*)d_in[0];   // (256, 64)
    const float* base = (const float*)d_in[1];   // (64, 100, 10000)
    float*       out  = (float*)d_out;           // (256, 10000)
    ushort*      part = (ushort*)d_ws;                         // bf16 partials
    uint*        prm  = (uint*)((char*)d_ws + PRM_OFF_BYTES);  // packed params

    setup_kernel<<<DIMS, 256, 0, stream>>>(x, prm);
    dim3 grid(NHT, DSPLIT);
    encode_kernel<<<grid, TPB, 0, stream>>>(base, prm, part);
    finish_kernel<<<BATCH, 256, 0, stream>>>(part, out);
}